// Round 1
// baseline (1431.358 us; speedup 1.0000x reference)
//
#include <hip/hip_runtime.h>
#include <hip/hip_bf16.h>

// Problem constants (reference: VOCAB=32000, EMBED=512, HIDDEN=1024, ATT_L=64, MAX_LEN=32, BATCH=64)
#define T_STEPS 31        // MAX_LEN - 1
#define B_ 64
#define E_ 512
#define H_ 1024
#define G4 4096           // 4*HIDDEN gates
#define V_ 32000
#define MPAD 2048         // T_STEPS*B_=1984 padded to multiple of 128

typedef __bf16 bf16x8_t __attribute__((ext_vector_type(8)));
typedef float f32x4_t __attribute__((ext_vector_type(4)));
typedef unsigned short u16x8_t __attribute__((ext_vector_type(8)));
using bf16 = __hip_bfloat16;

// ---------------------------------------------------------------------------
// Generic bf16 GEMM, C = A @ BT^T (+bias) (+accumulate)
// A: M(padded rows valid)×K row-major bf16; BT: N×K row-major bf16; C: M×N fp32.
// mfma_f32_16x16x32_bf16. A-frag: [m=lane&15][k=(lane>>4)*8+j]; B-frag same on BT rows.
// C/D: col=lane&15, row=(lane>>4)*4+reg  [measured m89].
// LDS rows padded +8 bf16 (stride 144B): b128 frag reads land 2-way bank aliased = free.
// ---------------------------------------------------------------------------
template<int BM, int BN, int WM, int WN>
__global__ __launch_bounds__(256)
void gemm_bt(const bf16* __restrict__ A, const bf16* __restrict__ BT,
             float* __restrict__ C, const float* __restrict__ bias,
             int M, int N, int K, int accumulate)
{
    constexpr int BK = 64;
    constexpr int LDT = BK + 8;
    constexpr int WCOLS = BN / WN;
    constexpr int MI = WM / 16, NI = WN / 16;
    constexpr int AVEC = BM * BK / 8 / 256;
    constexpr int BVEC = BN * BK / 8 / 256;
    static_assert((BM / WM) * (BN / WN) == 4, "4 waves");

    __shared__ bf16 As[BM * LDT];
    __shared__ bf16 Bs[BN * LDT];

    const int tid = threadIdx.x;
    const int lane = tid & 63;
    const int w = tid >> 6;
    const int wr = w / WCOLS, wc = w % WCOLS;
    const int m0 = blockIdx.y * BM;
    const int n0 = blockIdx.x * BN;
    const int quad = lane >> 4;
    const int l16 = lane & 15;

    f32x4_t acc[MI][NI];
#pragma unroll
    for (int i = 0; i < MI; i++)
#pragma unroll
        for (int j = 0; j < NI; j++) acc[i][j] = f32x4_t{0.f, 0.f, 0.f, 0.f};

    for (int kt = 0; kt < K; kt += BK) {
#pragma unroll
        for (int v = 0; v < AVEC; v++) {
            int idx = tid + v * 256;
            int row = idx >> 3;            // BK/8 = 8 vectors per row
            int col = (idx & 7) << 3;
            u16x8_t val = *reinterpret_cast<const u16x8_t*>(A + (size_t)(m0 + row) * K + kt + col);
            *reinterpret_cast<u16x8_t*>(&As[row * LDT + col]) = val;
        }
#pragma unroll
        for (int v = 0; v < BVEC; v++) {
            int idx = tid + v * 256;
            int row = idx >> 3;
            int col = (idx & 7) << 3;
            u16x8_t val = *reinterpret_cast<const u16x8_t*>(BT + (size_t)(n0 + row) * K + kt + col);
            *reinterpret_cast<u16x8_t*>(&Bs[row * LDT + col]) = val;
        }
        __syncthreads();
#pragma unroll
        for (int kk = 0; kk < BK; kk += 32) {
            bf16x8_t af[MI], bfr[NI];
#pragma unroll
            for (int i = 0; i < MI; i++) {
                u16x8_t t8 = *reinterpret_cast<const u16x8_t*>(
                    &As[(wr * WM + i * 16 + l16) * LDT + kk + quad * 8]);
                af[i] = __builtin_bit_cast(bf16x8_t, t8);
            }
#pragma unroll
            for (int j = 0; j < NI; j++) {
                u16x8_t t8 = *reinterpret_cast<const u16x8_t*>(
                    &Bs[(wc * WN + j * 16 + l16) * LDT + kk + quad * 8]);
                bfr[j] = __builtin_bit_cast(bf16x8_t, t8);
            }
#pragma unroll
            for (int i = 0; i < MI; i++)
#pragma unroll
                for (int j = 0; j < NI; j++)
                    acc[i][j] = __builtin_amdgcn_mfma_f32_16x16x32_bf16(af[i], bfr[j], acc[i][j], 0, 0, 0);
        }
        __syncthreads();
    }

#pragma unroll
    for (int i = 0; i < MI; i++) {
        int rbase = m0 + wr * WM + i * 16 + quad * 4;
#pragma unroll
        for (int j = 0; j < NI; j++) {
            int coln = n0 + wc * WN + j * 16 + l16;
            float badd = bias ? bias[coln] : 0.f;
#pragma unroll
            for (int r = 0; r < 4; r++) {
                int grow = rbase + r;
                if (grow < M) {
                    size_t ci = (size_t)grow * N + coln;
                    float val = acc[i][j][r] + badd;
                    if (accumulate) C[ci] += val; else C[ci] = val;
                }
            }
        }
    }
}

// ---------------------------------------------------------------------------
// Prep kernels
// ---------------------------------------------------------------------------

// ctx[b] = sum_l features[b][l][:]  (softmax over singleton dim == uniform weights)
// Split into bf16 hi+lo for high-precision ctx@Wc GEMM (ctx magnitude ~8, systematic error path).
__global__ void ctx_kernel(const float* __restrict__ features, bf16* __restrict__ hi, bf16* __restrict__ lo)
{
    int b = blockIdx.x;
    for (int j = threadIdx.x; j < H_; j += 256) {
        float s = 0.f;
        const float* f = features + (size_t)b * 64 * H_ + j;
#pragma unroll
        for (int l = 0; l < 64; l++) s += f[(size_t)l * H_];
        bf16 h = __float2bfloat16(s);
        hi[b * H_ + j] = h;
        lo[b * H_ + j] = __float2bfloat16(s - __bfloat162float(h));
    }
}

__global__ void bias_kernel(const float* __restrict__ bi, const float* __restrict__ bh, float* __restrict__ bc)
{
    int g = blockIdx.x * 256 + threadIdx.x;
    if (g < G4) bc[g] = bi[g] + bh[g];
}

// xs[t*B+b][e] = bf16(embed[captions[b][t]][e]); pad rows [1984,2048) zeroed
__global__ void gather_embed(const int* __restrict__ captions, const float* __restrict__ table,
                             bf16* __restrict__ xs)
{
    int idx = blockIdx.x * 256 + threadIdx.x;   // < MPAD*E_
    int tb = idx >> 9, e = idx & (E_ - 1);
    float v = 0.f;
    if (tb < T_STEPS * B_) {
        int t = tb >> 6, b = tb & 63;
        int tok = captions[b * 32 + t];          // captions row-major (B, MAX_LEN=32)
        v = table[(size_t)tok * E_ + e];
    }
    xs[idx] = __float2bfloat16(v);
}

// fp32 (rows x cols slice of strided src) -> bf16 (+optional lo residual)
__global__ void cvt_bf16(const float* __restrict__ src, bf16* __restrict__ hi, bf16* __restrict__ lo,
                         int rows, int cols, int stride, int off)
{
    long i4 = (long)blockIdx.x * 256 + threadIdx.x;
    long total = (long)rows * cols / 4;
    if (i4 >= total) return;
    long e = i4 * 4;
    int r = (int)(e / cols);
    int ci = (int)(e % cols);
    f32x4_t v = *reinterpret_cast<const f32x4_t*>(src + (size_t)r * stride + off + ci);
#pragma unroll
    for (int q = 0; q < 4; q++) {
        bf16 h = __float2bfloat16(v[q]);
        hi[e + q] = h;
        if (lo) lo[e + q] = __float2bfloat16(v[q] - __bfloat162float(h));
    }
}

__global__ void zero_f32(float* __restrict__ p, int n)
{
    int i = blockIdx.x * 256 + threadIdx.x;
    if (i < n) p[i] = 0.f;
}
__global__ void zero_bf16(bf16* __restrict__ p, int n)
{
    int i = blockIdx.x * 256 + threadIdx.x;
    if (i < n) p[i] = __float2bfloat16(0.f);
}

// ---------------------------------------------------------------------------
// Per-step LSTM pointwise update (PyTorch gate order i,f,g,o)
// gates = pre_x[tb] + ctxW[b] + bc + hW[b]
// ---------------------------------------------------------------------------
__global__ void lstm_update(const float* __restrict__ pre_x, const float* __restrict__ ctxW,
                            const float* __restrict__ bc, const float* __restrict__ hW,
                            float* __restrict__ c, bf16* __restrict__ h_bf,
                            bf16* __restrict__ hs, int t)
{
    int idx = blockIdx.x * 256 + threadIdx.x;   // < B_*H_
    int b = idx >> 10, j = idx & (H_ - 1);
    size_t tb = (size_t)t * B_ + b;
    const float* pg = pre_x + tb * G4;
    const float* cw = ctxW + (size_t)b * G4;
    const float* hw = hW + (size_t)b * G4;
    float gi = pg[j]          + cw[j]          + bc[j]          + hw[j];
    float gf = pg[H_ + j]     + cw[H_ + j]     + bc[H_ + j]     + hw[H_ + j];
    float gg = pg[2 * H_ + j] + cw[2 * H_ + j] + bc[2 * H_ + j] + hw[2 * H_ + j];
    float go = pg[3 * H_ + j] + cw[3 * H_ + j] + bc[3 * H_ + j] + hw[3 * H_ + j];
    float si = 1.f / (1.f + expf(-gi));
    float sf = 1.f / (1.f + expf(-gf));
    float so = 1.f / (1.f + expf(-go));
    float tg = tanhf(gg);
    float cn = sf * c[idx] + si * tg;
    float hn = so * tanhf(cn);
    c[idx] = cn;
    bf16 hb = __float2bfloat16(hn);
    h_bf[idx] = hb;                 // next step's GEMM A operand
    hs[tb * H_ + j] = hb;           // collected for final logits GEMM
}

// ---------------------------------------------------------------------------
extern "C" void kernel_launch(void* const* d_in, const int* in_sizes, int n_in,
                              void* d_out, int out_size, void* d_ws, size_t ws_size,
                              hipStream_t stream)
{
    (void)in_sizes; (void)n_in; (void)out_size; (void)ws_size;
    const float* features = (const float*)d_in[0];
    const int*   captions = (const int*)d_in[1];
    // d_in[2] lengths: unused (full lengths). d_in[8]/d_in[9] attn: dead code (softmax over singleton).
    const float* embed    = (const float*)d_in[3];
    const float* W_ih     = (const float*)d_in[4];
    const float* W_hh     = (const float*)d_in[5];
    const float* b_ih     = (const float*)d_in[6];
    const float* b_hh     = (const float*)d_in[7];
    const float* lin_W    = (const float*)d_in[10];
    const float* lin_b    = (const float*)d_in[11];
    float* out = (float*)d_out;

    char* wp = (char*)d_ws;
    auto alloc = [&](size_t bytes) -> void* {
        void* p = (void*)wp;
        wp += (bytes + 255) & ~(size_t)255;
        return p;
    };
    bf16*  ctx_hi = (bf16*)alloc((size_t)B_ * H_ * 2);
    bf16*  ctx_lo = (bf16*)alloc((size_t)B_ * H_ * 2);
    float* bc     = (float*)alloc((size_t)G4 * 4);
    bf16*  xs     = (bf16*)alloc((size_t)MPAD * E_ * 2);
    bf16*  Wx     = (bf16*)alloc((size_t)G4 * E_ * 2);
    bf16*  Wc_hi  = (bf16*)alloc((size_t)G4 * H_ * 2);
    bf16*  Wc_lo  = (bf16*)alloc((size_t)G4 * H_ * 2);
    bf16*  Whh    = (bf16*)alloc((size_t)G4 * H_ * 2);
    bf16*  WlinB  = (bf16*)alloc((size_t)V_ * H_ * 2);
    float* pre_x  = (float*)alloc((size_t)T_STEPS * B_ * G4 * 4);
    float* ctxW   = (float*)alloc((size_t)B_ * G4 * 4);
    float* hW     = (float*)alloc((size_t)B_ * G4 * 4);
    float* cbuf   = (float*)alloc((size_t)B_ * H_ * 4);
    bf16*  h_bf   = (bf16*)alloc((size_t)B_ * H_ * 2);
    bf16*  hs     = (bf16*)alloc((size_t)MPAD * H_ * 2);

    // ---- prep (every call: ws is re-poisoned to 0xAA before each timed launch) ----
    bias_kernel<<<16, 256, 0, stream>>>(b_ih, b_hh, bc);
    ctx_kernel<<<B_, 256, 0, stream>>>(features, ctx_hi, ctx_lo);
    gather_embed<<<MPAD * E_ / 256, 256, 0, stream>>>(captions, embed, xs);
    cvt_bf16<<<G4 * E_ / 4 / 256, 256, 0, stream>>>(W_ih, Wx, nullptr, G4, E_, E_ + H_, 0);
    cvt_bf16<<<G4 * H_ / 4 / 256, 256, 0, stream>>>(W_ih, Wc_hi, Wc_lo, G4, H_, E_ + H_, E_);
    cvt_bf16<<<G4 * H_ / 4 / 256, 256, 0, stream>>>(W_hh, Whh, nullptr, G4, H_, H_, 0);
    cvt_bf16<<<V_ * (H_ / 4) / 256, 256, 0, stream>>>(lin_W, WlinB, nullptr, V_, H_, H_, 0);
    zero_f32<<<B_ * H_ / 256, 256, 0, stream>>>(cbuf, B_ * H_);
    zero_bf16<<<B_ * H_ / 256, 256, 0, stream>>>(h_bf, B_ * H_);
    zero_bf16<<<(MPAD - T_STEPS * B_) * H_ / 256, 256, 0, stream>>>(
        hs + (size_t)T_STEPS * B_ * H_, (MPAD - T_STEPS * B_) * H_);

    // ---- ctxW (once; hi/lo split kills the systematic bf16 error on the ctx path) ----
    gemm_bt<64, 128, 64, 32><<<dim3(G4 / 128, 1), 256, 0, stream>>>(ctx_hi, Wc_hi, ctxW, nullptr, B_, G4, H_, 0);
    gemm_bt<64, 128, 64, 32><<<dim3(G4 / 128, 1), 256, 0, stream>>>(ctx_lo, Wc_hi, ctxW, nullptr, B_, G4, H_, 1);
    gemm_bt<64, 128, 64, 32><<<dim3(G4 / 128, 1), 256, 0, stream>>>(ctx_hi, Wc_lo, ctxW, nullptr, B_, G4, H_, 1);

    // ---- pre_x = xs @ Wx^T for all 31 steps at once (M=1984, N=4096, K=512) ----
    gemm_bt<128, 128, 64, 64><<<dim3(G4 / 128, MPAD / 128), 256, 0, stream>>>(
        xs, Wx, pre_x, nullptr, T_STEPS * B_, G4, E_, 0);

    // ---- sequential recurrence: only h@W_hh^T (64x4096, K=1024) per step ----
    for (int t = 0; t < T_STEPS; t++) {
        gemm_bt<64, 128, 64, 32><<<dim3(G4 / 128, 1), 256, 0, stream>>>(h_bf, Whh, hW, nullptr, B_, G4, H_, 0);
        lstm_update<<<B_ * H_ / 256, 256, 0, stream>>>(pre_x, ctxW, bc, hW, cbuf, h_bf, hs, t);
    }

    // ---- logits = hs @ lin_W^T + lin_b (M=1984, N=32000, K=1024) -> d_out ----
    gemm_bt<128, 128, 64, 64><<<dim3(V_ / 128, MPAD / 128), 256, 0, stream>>>(
        hs, WlinB, out, lin_b, T_STEPS * B_, V_, H_, 0);
}

// Round 2
// 1229.150 us; speedup vs baseline: 1.1645x; 1.1645x over previous
//
#include <hip/hip_runtime.h>
#include <hip/hip_bf16.h>
#include <stdint.h>

// Problem constants (VOCAB=32000, EMBED=512, HIDDEN=1024, ATT_L=64, MAX_LEN=32, BATCH=64)
#define T_STEPS 31        // MAX_LEN - 1
#define B_ 64
#define E_ 512
#define H_ 1024
#define G4 4096           // 4*HIDDEN gates
#define V_ 32000
#define MPAD 2048         // T_STEPS*B_=1984 padded to 128-multiple

typedef __bf16 bf16x8_t __attribute__((ext_vector_type(8)));
typedef float f32x4_t __attribute__((ext_vector_type(4)));
typedef unsigned short u16x8_t __attribute__((ext_vector_type(8)));
using bf16 = __hip_bfloat16;

typedef const __attribute__((address_space(1))) unsigned int gas_u32;
typedef __attribute__((address_space(3))) unsigned int las_u32;

// Async global->LDS, 16B per lane. LDS dest must be wave-uniform base + lane*16
// (m104/m108: no per-lane scatter, no padding). Width=16 was the 517->874 TF step (m97).
__device__ __forceinline__ void async16(const bf16* g, bf16* l) {
    __builtin_amdgcn_global_load_lds((gas_u32*)(uintptr_t)g, (las_u32*)(uintptr_t)l, 16, 0, 0);
}

// ---------------------------------------------------------------------------
// m97-style GEMM: C = A @ BT^T (+bias) (+accumulate)
// A: M×K row-major bf16 (rows padded to BM-multiple, pad rows zeroed by caller)
// BT: N×K row-major bf16; C: M×N fp32.
// BK=32: LDS rows are 64B stride -> frag ds_read_b128 lands 2-way bank-aliased (free, m136).
// Unpadded LDS (global_load_lds requires it). 2x2 waves, wave tile (BM/2)x(BN/2).
// grid: (x = m-blocks, y = n-blocks) -> consecutive blocks share the B-tile (L2 locality).
// ---------------------------------------------------------------------------
template<int BM, int BN>
__global__ __launch_bounds__(256)
void gemm_lds(const bf16* __restrict__ A, const bf16* __restrict__ BT,
              float* __restrict__ C, const float* __restrict__ bias,
              int M, int N, int K, int accumulate)
{
    constexpr int BK = 32;
    constexpr int WM = BM / 2, WN = BN / 2;
    constexpr int MI = WM / 16, NI = WN / 16;
    constexpr int AV = (BM * BK) / (8 * 256);   // 16B stages per thread for A-tile
    constexpr int BV = (BN * BK) / (8 * 256);
    static_assert(AV >= 1 && BV >= 1, "tile too small for staging");

    __shared__ bf16 As[BM * BK];
    __shared__ bf16 Bs[BN * BK];

    const int tid = threadIdx.x;
    const int lane = tid & 63;
    const int w = tid >> 6;
    const int wr = w >> 1, wc = w & 1;
    const int quad = lane >> 4, l16 = lane & 15;
    const int m0 = blockIdx.x * BM;
    const int n0 = blockIdx.y * BN;

    f32x4_t acc[MI][NI];
#pragma unroll
    for (int i = 0; i < MI; i++)
#pragma unroll
        for (int j = 0; j < NI; j++) acc[i][j] = f32x4_t{0.f, 0.f, 0.f, 0.f};

    for (int kt = 0; kt < K; kt += BK) {
#pragma unroll
        for (int v = 0; v < AV; v++) {
            int idx = tid + v * 256;
            int row = idx >> 2, col = (idx & 3) << 3;   // 4 lanes per 32-elem row
            async16(A + (size_t)(m0 + row) * K + kt + col, As + idx * 8);
        }
#pragma unroll
        for (int v = 0; v < BV; v++) {
            int idx = tid + v * 256;
            int row = idx >> 2, col = (idx & 3) << 3;
            async16(BT + (size_t)(n0 + row) * K + kt + col, Bs + idx * 8);
        }
        __syncthreads();

        bf16x8_t af[MI], bfr[NI];
#pragma unroll
        for (int i = 0; i < MI; i++)
            af[i] = __builtin_bit_cast(bf16x8_t,
                *reinterpret_cast<const u16x8_t*>(&As[(wr * WM + i * 16 + l16) * BK + quad * 8]));
#pragma unroll
        for (int j = 0; j < NI; j++)
            bfr[j] = __builtin_bit_cast(bf16x8_t,
                *reinterpret_cast<const u16x8_t*>(&Bs[(wc * WN + j * 16 + l16) * BK + quad * 8]));
#pragma unroll
        for (int i = 0; i < MI; i++)
#pragma unroll
            for (int j = 0; j < NI; j++)
                acc[i][j] = __builtin_amdgcn_mfma_f32_16x16x32_bf16(af[i], bfr[j], acc[i][j], 0, 0, 0);
        __syncthreads();
    }

    // C/D layout: col=lane&15, row=quad*4+reg (m89)
#pragma unroll
    for (int i = 0; i < MI; i++) {
        int rbase = m0 + wr * WM + i * 16 + quad * 4;
#pragma unroll
        for (int j = 0; j < NI; j++) {
            int coln = n0 + wc * WN + j * 16 + l16;
            float badd = bias ? bias[coln] : 0.f;
#pragma unroll
            for (int r = 0; r < 4; r++) {
                int grow = rbase + r;
                if (grow < M) {
                    size_t ci = (size_t)grow * N + coln;
                    float val = acc[i][j][r] + badd;
                    if (accumulate) C[ci] += val; else C[ci] = val;
                }
            }
        }
    }
}

// ---------------------------------------------------------------------------
// Fused per-step kernel: gates = pre_x[t] + ctxW + bc + h@Whh^T, then LSTM
// pointwise in the epilogue. All gate tensors use PERMUTED columns p = j*4+g
// (g: 0=i,1=f,2=cellg,3=o) so one 64-col block owns complete j-groups.
// BM=64(batch), BN=64 gate-cols, grid 64 blocks.
// ---------------------------------------------------------------------------
__global__ __launch_bounds__(256)
void step_fused(const bf16* __restrict__ h_in, const bf16* __restrict__ Whh,
                const float* __restrict__ pre_x, const float* __restrict__ ctxW,
                const float* __restrict__ bc, float* __restrict__ c,
                bf16* __restrict__ h_out, bf16* __restrict__ hs, int t)
{
    constexpr int BK = 32;
    constexpr int K = H_;
    __shared__ bf16 As[64 * BK];
    __shared__ bf16 Bs[64 * BK];
    __shared__ float gates[64 * 65];   // +1 pad

    const int tid = threadIdx.x;
    const int lane = tid & 63;
    const int w = tid >> 6;
    const int wr = w >> 1, wc = w & 1;          // 2x2 waves, wave tile 32x32
    const int quad = lane >> 4, l16 = lane & 15;
    const int n0 = blockIdx.x * 64;

    f32x4_t acc[2][2];
#pragma unroll
    for (int i = 0; i < 2; i++)
#pragma unroll
        for (int j = 0; j < 2; j++) acc[i][j] = f32x4_t{0.f, 0.f, 0.f, 0.f};

    for (int kt = 0; kt < K; kt += BK) {
        {
            int row = tid >> 2, col = (tid & 3) << 3;
            async16(h_in + (size_t)row * K + kt + col, As + tid * 8);
            async16(Whh + (size_t)(n0 + row) * K + kt + col, Bs + tid * 8);
        }
        __syncthreads();
        bf16x8_t af[2], bfr[2];
#pragma unroll
        for (int i = 0; i < 2; i++)
            af[i] = __builtin_bit_cast(bf16x8_t,
                *reinterpret_cast<const u16x8_t*>(&As[(wr * 32 + i * 16 + l16) * BK + quad * 8]));
#pragma unroll
        for (int j = 0; j < 2; j++)
            bfr[j] = __builtin_bit_cast(bf16x8_t,
                *reinterpret_cast<const u16x8_t*>(&Bs[(wc * 32 + j * 16 + l16) * BK + quad * 8]));
#pragma unroll
        for (int i = 0; i < 2; i++)
#pragma unroll
            for (int j = 0; j < 2; j++)
                acc[i][j] = __builtin_amdgcn_mfma_f32_16x16x32_bf16(af[i], bfr[j], acc[i][j], 0, 0, 0);
        __syncthreads();
    }

    // gate assembly into LDS: gates[b][col] = acc + pre_x + ctxW + bc
#pragma unroll
    for (int i = 0; i < 2; i++) {
        int rbase = wr * 32 + i * 16 + quad * 4;
#pragma unroll
        for (int j = 0; j < 2; j++) {
            int col = wc * 32 + j * 16 + l16;
            int gcol = n0 + col;
            float badd = bc[gcol];
#pragma unroll
            for (int r = 0; r < 4; r++) {
                int b = rbase + r;
                gates[b * 65 + col] = acc[i][j][r] + badd
                    + pre_x[((size_t)t * B_ + b) * G4 + gcol]
                    + ctxW[(size_t)b * G4 + gcol];
            }
        }
    }
    __syncthreads();

    // LSTM pointwise: 64 b × 16 j per block = 1024 items, 4 per thread
#pragma unroll
    for (int v = 0; v < 4; v++) {
        int item = tid + v * 256;
        int b = item >> 4, jj = item & 15;
        float gi = gates[b * 65 + jj * 4 + 0];
        float gf = gates[b * 65 + jj * 4 + 1];
        float gg = gates[b * 65 + jj * 4 + 2];
        float go = gates[b * 65 + jj * 4 + 3];
        int j = (n0 >> 2) + jj;
        int idx = b * H_ + j;
        float si = 1.f / (1.f + expf(-gi));
        float sf = 1.f / (1.f + expf(-gf));
        float so = 1.f / (1.f + expf(-go));
        float cn = sf * c[idx] + si * tanhf(gg);
        float hn = so * tanhf(cn);
        c[idx] = cn;
        bf16 hb = __float2bfloat16(hn);
        h_out[idx] = hb;
        hs[((size_t)t * B_ + b) * H_ + j] = hb;
    }
}

// ---------------------------------------------------------------------------
// Prep kernels
// ---------------------------------------------------------------------------

// ctx[b] = sum_l features[b][l][:] (softmax over singleton dim == uniform). hi/lo bf16 split.
__global__ void ctx_kernel(const float* __restrict__ features, bf16* __restrict__ hi, bf16* __restrict__ lo)
{
    int b = blockIdx.x;
    for (int j = threadIdx.x; j < H_; j += 256) {
        float s = 0.f;
        const float* f = features + (size_t)b * 64 * H_ + j;
#pragma unroll
        for (int l = 0; l < 64; l++) s += f[(size_t)l * H_];
        bf16 h = __float2bfloat16(s);
        hi[b * H_ + j] = h;
        lo[b * H_ + j] = __float2bfloat16(s - __bfloat162float(h));
    }
}

// bc[perm(g)] = b_ih[g] + b_hh[g], perm(g) = (g%H)*4 + g/H
__global__ void bias_kernel(const float* __restrict__ bi, const float* __restrict__ bh, float* __restrict__ bc)
{
    int g = blockIdx.x * 256 + threadIdx.x;
    if (g < G4) bc[(g & (H_ - 1)) * 4 + (g >> 10)] = bi[g] + bh[g];
}

// xs[t*B+b][e] = bf16(embed[captions[b][t]][e]); pad rows zeroed
__global__ void gather_embed(const int* __restrict__ captions, const float* __restrict__ table,
                             bf16* __restrict__ xs)
{
    int idx = blockIdx.x * 256 + threadIdx.x;   // < MPAD*E_
    int tb = idx >> 9, e = idx & (E_ - 1);
    float v = 0.f;
    if (tb < T_STEPS * B_) {
        int t = tb >> 6, b = tb & 63;
        int tok = captions[b * 32 + t];
        v = table[(size_t)tok * E_ + e];
    }
    xs[idx] = __float2bfloat16(v);
}

// fp32 (rows x cols slice of strided src) -> bf16 (+optional lo residual), optional gate-row permute
__global__ void cvt_bf16(const float* __restrict__ src, bf16* __restrict__ hi, bf16* __restrict__ lo,
                         int rows, int cols, int stride, int off, int perm)
{
    long i4 = (long)blockIdx.x * 256 + threadIdx.x;
    long total = (long)rows * cols / 4;
    if (i4 >= total) return;
    long e = i4 * 4;
    int r = (int)(e / cols);
    int ci = (int)(e % cols);
    int ro = perm ? ((r & (H_ - 1)) * 4 + (r >> 10)) : r;
    f32x4_t v = *reinterpret_cast<const f32x4_t*>(src + (size_t)r * stride + off + ci);
    size_t ob = (size_t)ro * cols + ci;
#pragma unroll
    for (int q = 0; q < 4; q++) {
        bf16 h = __float2bfloat16(v[q]);
        hi[ob + q] = h;
        if (lo) lo[ob + q] = __float2bfloat16(v[q] - __bfloat162float(h));
    }
}

__global__ void zero_f32(float* __restrict__ p, int n)
{
    int i = blockIdx.x * 256 + threadIdx.x;
    if (i < n) p[i] = 0.f;
}
__global__ void zero_bf16(bf16* __restrict__ p, int n)
{
    int i = blockIdx.x * 256 + threadIdx.x;
    if (i < n) p[i] = __float2bfloat16(0.f);
}

// ---------------------------------------------------------------------------
extern "C" void kernel_launch(void* const* d_in, const int* in_sizes, int n_in,
                              void* d_out, int out_size, void* d_ws, size_t ws_size,
                              hipStream_t stream)
{
    (void)in_sizes; (void)n_in; (void)out_size; (void)ws_size;
    const float* features = (const float*)d_in[0];
    const int*   captions = (const int*)d_in[1];
    // d_in[2] lengths unused (full). d_in[8]/d_in[9] attn_W/b: dead (softmax over singleton dim).
    const float* embed    = (const float*)d_in[3];
    const float* W_ih     = (const float*)d_in[4];
    const float* W_hh     = (const float*)d_in[5];
    const float* b_ih     = (const float*)d_in[6];
    const float* b_hh     = (const float*)d_in[7];
    const float* lin_W    = (const float*)d_in[10];
    const float* lin_b    = (const float*)d_in[11];
    float* out = (float*)d_out;

    char* wp = (char*)d_ws;
    auto alloc = [&](size_t bytes) -> void* {
        void* p = (void*)wp;
        wp += (bytes + 255) & ~(size_t)255;
        return p;
    };
    bf16*  ctx_hi = (bf16*)alloc((size_t)B_ * H_ * 2);
    bf16*  ctx_lo = (bf16*)alloc((size_t)B_ * H_ * 2);
    float* bc     = (float*)alloc((size_t)G4 * 4);
    bf16*  xs     = (bf16*)alloc((size_t)MPAD * E_ * 2);
    bf16*  Wx     = (bf16*)alloc((size_t)G4 * E_ * 2);      // gate-permuted rows
    bf16*  Wc_hi  = (bf16*)alloc((size_t)G4 * H_ * 2);      // gate-permuted rows
    bf16*  Wc_lo  = (bf16*)alloc((size_t)G4 * H_ * 2);
    bf16*  Whh    = (bf16*)alloc((size_t)G4 * H_ * 2);      // gate-permuted rows
    bf16*  WlinB  = (bf16*)alloc((size_t)V_ * H_ * 2);
    float* pre_x  = (float*)alloc((size_t)T_STEPS * B_ * G4 * 4);  // permuted cols
    float* ctxW   = (float*)alloc((size_t)B_ * G4 * 4);            // permuted cols
    float* cbuf   = (float*)alloc((size_t)B_ * H_ * 4);
    bf16*  h_bf   = (bf16*)alloc((size_t)B_ * H_ * 2);
    bf16*  hs     = (bf16*)alloc((size_t)MPAD * H_ * 2);

    // ---- prep (re-run every call: ws re-poisoned before each timed launch) ----
    bias_kernel<<<16, 256, 0, stream>>>(b_ih, b_hh, bc);
    ctx_kernel<<<B_, 256, 0, stream>>>(features, ctx_hi, ctx_lo);
    gather_embed<<<MPAD * E_ / 256, 256, 0, stream>>>(captions, embed, xs);
    cvt_bf16<<<G4 * E_ / 4 / 256, 256, 0, stream>>>(W_ih, Wx, nullptr, G4, E_, E_ + H_, 0, 1);
    cvt_bf16<<<G4 * H_ / 4 / 256, 256, 0, stream>>>(W_ih, Wc_hi, Wc_lo, G4, H_, E_ + H_, E_, 1);
    cvt_bf16<<<G4 * H_ / 4 / 256, 256, 0, stream>>>(W_hh, Whh, nullptr, G4, H_, H_, 0, 1);
    cvt_bf16<<<V_ * (H_ / 4) / 256, 256, 0, stream>>>(lin_W, WlinB, nullptr, V_, H_, H_, 0, 0);
    zero_f32<<<B_ * H_ / 256, 256, 0, stream>>>(cbuf, B_ * H_);
    zero_bf16<<<B_ * H_ / 256, 256, 0, stream>>>(h_bf, B_ * H_);
    zero_bf16<<<(MPAD - T_STEPS * B_) * H_ / 256, 256, 0, stream>>>(
        hs + (size_t)T_STEPS * B_ * H_, (MPAD - T_STEPS * B_) * H_);

    // ---- ctxW (once; hi/lo split kills systematic bf16 error on ctx path) ----
    gemm_lds<64, 64><<<dim3(1, G4 / 64), 256, 0, stream>>>(ctx_hi, Wc_hi, ctxW, nullptr, B_, G4, H_, 0);
    gemm_lds<64, 64><<<dim3(1, G4 / 64), 256, 0, stream>>>(ctx_lo, Wc_hi, ctxW, nullptr, B_, G4, H_, 1);
    gemm_lds<64, 64><<<dim3(1, G4 / 64), 256, 0, stream>>>(ctx_hi, Wc_lo, ctxW, nullptr, B_, G4, H_, 1);

    // ---- pre_x = xs @ Wx^T for all steps (M=1984, N=4096, K=512) ----
    gemm_lds<128, 128><<<dim3(MPAD / 128, G4 / 128), 256, 0, stream>>>(
        xs, Wx, pre_x, nullptr, T_STEPS * B_, G4, E_, 0);

    // ---- recurrence: one fused kernel per step ----
    for (int t = 0; t < T_STEPS; t++)
        step_fused<<<G4 / 64, 256, 0, stream>>>(h_bf, Whh, pre_x, ctxW, bc, cbuf, h_bf, hs, t);

    // ---- logits = hs @ lin_W^T + lin_b (M=1984, N=32000, K=1024) ----
    gemm_lds<128, 128><<<dim3(MPAD / 128, V_ / 128), 256, 0, stream>>>(
        hs, WlinB, out, lin_b, T_STEPS * B_, V_, H_, 0);
}